// Round 2
// baseline (4069.449 us; speedup 1.0000x reference)
//
#include <hip/hip_runtime.h>
#include <hip/hip_bf16.h>

#define BB   2
#define LL   21
#define CC   3
#define HH   512
#define WW   512
#define RR   20
#define NCH  84            // LL + CC*LL planes per batch (p, then I_c*p)
#define HW   (HH*WW)       // 262144 = 2^18
#define VSEG 128           // rows per vbox thread
#define TR   8             // rows per hbox block
#define LROW 544           // 512 + 512/16 skew pad
#define SKW(i) ((i) + ((i) >> 4))

__device__ __forceinline__ float nrminv(int x, int y) {
    int cx = min(x + RR, WW - 1) - max(x - RR, 0) + 1;
    int cy = min(y + RR, HH - 1) - max(y - RR, 0) + 1;
    return 1.0f / (float)(cx * cy);
}

// ---- products: I and I*I planes into P -------------------------------------
__global__ __launch_bounds__(256) void prod_k(float* __restrict__ P,
                                              const float* __restrict__ Refs) {
    int idx = blockIdx.x * 256 + threadIdx.x;
    int b = idx >> 18, pix = idx & (HW - 1);
    float I0 = Refs[((size_t)b * 3 + 0) * HW + pix];
    float I1 = Refs[((size_t)b * 3 + 1) * HW + pix];
    float I2 = Refs[((size_t)b * 3 + 2) * HW + pix];
    size_t base = (size_t)b * NCH * HW + pix;
    P[base + (size_t)0 * HW] = I0;
    P[base + (size_t)1 * HW] = I1;
    P[base + (size_t)2 * HW] = I2;
    P[base + (size_t)3 * HW] = I0 * I0;
    P[base + (size_t)4 * HW] = I0 * I1;
    P[base + (size_t)5 * HW] = I0 * I2;
    P[base + (size_t)6 * HW] = I1 * I1;
    P[base + (size_t)7 * HW] = I1 * I2;
    P[base + (size_t)8 * HW] = I2 * I2;
}

// ---- vertical box sum: P(strided planes) -> tmp(compact), sliding window ----
__global__ __launch_bounds__(256) void vbox_k(const float* __restrict__ src,
                                              float* __restrict__ dst, int c0, int n) {
    int pp = blockIdx.y;
    int b = pp / n, j = pp % n;
    const float* s = src + ((size_t)(b * NCH + c0 + j)) * HW;
    float* d = dst + (size_t)pp * HW;
    int x  = ((blockIdx.x & 1) << 8) + threadIdx.x;
    int y0 = (blockIdx.x >> 1) * VSEG;
    float sum = 0.f;
    int lo = y0 - RR; if (lo < 0) lo = 0;
    int hi = y0 + RR; if (hi > HH - 1) hi = HH - 1;
    for (int yy = lo; yy <= hi; ++yy) sum += s[(size_t)yy * WW + x];
    d[(size_t)y0 * WW + x] = sum;
    #pragma unroll 4
    for (int y = y0 + 1; y < y0 + VSEG; ++y) {
        int ya = y + RR, ys = y - RR - 1;
        if (ya < HH)  sum += s[(size_t)ya * WW + x];
        if (ys >= 0)  sum -= s[(size_t)ys * WW + x];
        d[(size_t)y * WW + x] = sum;
    }
}

// ---- horizontal box sum: tmp(compact) -> P(strided planes), LDS sliding ----
__global__ __launch_bounds__(256) void hbox_k(const float* __restrict__ src,
                                              float* __restrict__ dst, int c0, int n) {
    __shared__ float lin[TR * LROW];
    __shared__ float lout[TR * LROW];
    int pp = blockIdx.y;
    int b = pp / n, j = pp % n;
    const float* s = src + (size_t)pp * HW + (size_t)blockIdx.x * (TR * WW);
    float* d = dst + ((size_t)(b * NCH + c0 + j)) * HW + (size_t)blockIdx.x * (TR * WW);
    int tid = threadIdx.x;
    #pragma unroll
    for (int k = 0; k < (TR * WW) / 256; ++k) {
        int idx = tid + k * 256;
        int row = idx >> 9, xx = idx & (WW - 1);
        lin[row * LROW + SKW(xx)] = s[idx];
    }
    __syncthreads();
    int row = tid >> 5;
    int x0  = (tid & 31) << 4;              // 16 outputs per thread
    const float* in = lin + row * LROW;
    float* op = lout + row * LROW;
    float sum = 0.f;
    #pragma unroll
    for (int t = -RR; t <= RR; ++t) {       // prefill window [x0-20, x0+20]
        int i = x0 + t;
        if (i >= 0 && i < WW) sum += in[SKW(i)];
    }
    op[SKW(x0)] = sum;
    #pragma unroll
    for (int k = 1; k < 16; ++k) {
        int xx = x0 + k;
        int ia = xx + RR, is = xx - RR - 1;
        if (ia < WW)  sum += in[SKW(ia)];
        if (is >= 0)  sum -= in[SKW(is)];
        op[SKW(xx)] = sum;
    }
    __syncthreads();
    #pragma unroll
    for (int k = 0; k < (TR * WW) / 256; ++k) {
        int idx = tid + k * 256;
        int r2 = idx >> 9, xx = idx & (WW - 1);
        d[idx] = lout[r2 * LROW + SKW(xx)];
    }
}

// ---- precompute mI and Ainv = (var_I + eps I)^-1 (symmetric, 6 planes) -----
__global__ __launch_bounds__(256) void prep_k(const float* __restrict__ P,
                                              float* __restrict__ Ainv, float* __restrict__ mI,
                                              const float* __restrict__ epsp) {
    int idx = blockIdx.x * 256 + threadIdx.x;
    int b = idx >> 18, pix = idx & (HW - 1);
    int x = pix & (WW - 1), y = pix >> 9;
    float nrm = nrminv(x, y);
    float eps = epsp[0];
    size_t base = (size_t)b * NCH * HW + pix;
    float m0 = P[base + (size_t)0 * HW] * nrm;
    float m1 = P[base + (size_t)1 * HW] * nrm;
    float m2 = P[base + (size_t)2 * HW] * nrm;
    float v00 = P[base + (size_t)3 * HW] * nrm - m0 * m0 + eps;
    float v01 = P[base + (size_t)4 * HW] * nrm - m0 * m1;
    float v02 = P[base + (size_t)5 * HW] * nrm - m0 * m2;
    float v11 = P[base + (size_t)6 * HW] * nrm - m1 * m1 + eps;
    float v12 = P[base + (size_t)7 * HW] * nrm - m1 * m2;
    float v22 = P[base + (size_t)8 * HW] * nrm - m2 * m2 + eps;
    float c00 = v11 * v22 - v12 * v12;
    float c01 = v02 * v12 - v01 * v22;
    float c02 = v01 * v12 - v02 * v11;
    float c11 = v00 * v22 - v02 * v02;
    float c12 = v01 * v02 - v00 * v12;
    float c22 = v00 * v11 - v01 * v01;
    float det = v00 * c00 + v01 * c01 + v02 * c02;
    float id = 1.0f / det;
    size_t ab = (size_t)b * 6 * HW + pix;
    Ainv[ab + (size_t)0 * HW] = c00 * id;
    Ainv[ab + (size_t)1 * HW] = c01 * id;
    Ainv[ab + (size_t)2 * HW] = c02 * id;
    Ainv[ab + (size_t)3 * HW] = c11 * id;
    Ainv[ab + (size_t)4 * HW] = c12 * id;
    Ainv[ab + (size_t)5 * HW] = c22 * id;
    size_t mb = (size_t)b * 3 * HW + pix;
    mI[mb]                 = m0;
    mI[mb + (size_t)HW]    = m1;
    mI[mb + (size_t)2*HW]  = m2;
}

// ---- per-pixel 3x3 solve (in place): box(p),box(Ip) -> b,a -----------------
__global__ __launch_bounds__(256) void solve_k(float* __restrict__ P,
                                               const float* __restrict__ Ainv,
                                               const float* __restrict__ mI) {
    int idx = blockIdx.x * 256 + threadIdx.x;
    int b = idx >> 18, pix = idx & (HW - 1);
    int x = pix & (WW - 1), y = pix >> 9;
    float nrm = nrminv(x, y);
    size_t base = (size_t)b * NCH * HW + pix;
    size_t ab = (size_t)b * 6 * HW + pix;
    float iv0 = Ainv[ab + (size_t)0 * HW];
    float iv1 = Ainv[ab + (size_t)1 * HW];
    float iv2 = Ainv[ab + (size_t)2 * HW];
    float iv3 = Ainv[ab + (size_t)3 * HW];
    float iv4 = Ainv[ab + (size_t)4 * HW];
    float iv5 = Ainv[ab + (size_t)5 * HW];
    size_t mb = (size_t)b * 3 * HW + pix;
    float mi0 = mI[mb], mi1 = mI[mb + (size_t)HW], mi2 = mI[mb + (size_t)2*HW];
    for (int l = 0; l < LL; ++l) {
        float mp   = P[base + (size_t)l * HW] * nrm;
        float cov0 = P[base + (size_t)(LL + 0*LL + l) * HW] * nrm - mi0 * mp;
        float cov1 = P[base + (size_t)(LL + 1*LL + l) * HW] * nrm - mi1 * mp;
        float cov2 = P[base + (size_t)(LL + 2*LL + l) * HW] * nrm - mi2 * mp;
        float a0 = iv0 * cov0 + iv1 * cov1 + iv2 * cov2;
        float a1 = iv1 * cov0 + iv3 * cov1 + iv4 * cov2;
        float a2 = iv2 * cov0 + iv4 * cov1 + iv5 * cov2;
        float bb = mp - (a0 * mi0 + a1 * mi1 + a2 * mi2);
        P[base + (size_t)l * HW]               = bb;
        P[base + (size_t)(LL + 0*LL + l) * HW] = a0;
        P[base + (size_t)(LL + 1*LL + l) * HW] = a1;
        P[base + (size_t)(LL + 2*LL + l) * HW] = a2;
    }
}

// ---- fused: q = (boxa.I + boxb)/Nrm, E=E0+q, Q=softmax(-E), p=W.Q, Ip ------
// mode 0: init (skip q, E=E0);  mode 1: mid;  mode 2: last (write Q out)
__global__ __launch_bounds__(256) void e_k(float* __restrict__ P,
                                           const float* __restrict__ E0,
                                           const float* __restrict__ Refs,
                                           const float* __restrict__ Wf,
                                           float* __restrict__ out, int mode) {
    int idx = blockIdx.x * 256 + threadIdx.x;
    int b = idx >> 18, pix = idx & (HW - 1);
    int x = pix & (WW - 1), y = pix >> 9;
    float nrm = nrminv(x, y);
    size_t base  = (size_t)b * NCH * HW + pix;
    size_t ebase = (size_t)b * LL * HW + pix;
    float Ic0 = Refs[((size_t)b * 3 + 0) * HW + pix];
    float Ic1 = Refs[((size_t)b * 3 + 1) * HW + pix];
    float Ic2 = Refs[((size_t)b * 3 + 2) * HW + pix];
    float Ev[LL];
    float mmax = -1e30f;
    #pragma unroll
    for (int l = 0; l < LL; ++l) {
        float val = E0[ebase + (size_t)l * HW];
        if (mode != 0) {
            float s = P[base + (size_t)l * HW];
            s += P[base + (size_t)(LL + 0*LL + l) * HW] * Ic0;
            s += P[base + (size_t)(LL + 1*LL + l) * HW] * Ic1;
            s += P[base + (size_t)(LL + 2*LL + l) * HW] * Ic2;
            val += s * nrm;
        }
        float nv = -val;
        Ev[l] = nv;
        mmax = fmaxf(mmax, nv);
    }
    float ssum = 0.f;
    #pragma unroll
    for (int l = 0; l < LL; ++l) { float e = __expf(Ev[l] - mmax); Ev[l] = e; ssum += e; }
    float inv = 1.0f / ssum;
    if (mode == 2) {
        #pragma unroll
        for (int l = 0; l < LL; ++l)
            out[ebase + (size_t)l * HW] = Ev[l] * inv;
    } else {
        #pragma unroll
        for (int l = 0; l < LL; ++l) Ev[l] *= inv;      // Ev now holds Q
        #pragma unroll
        for (int l = 0; l < LL; ++l) {
            float p = 0.f;
            #pragma unroll
            for (int m = 0; m < LL; ++m) p += Wf[l * LL + m] * Ev[m];  // uniform addr -> s_load
            P[base + (size_t)l * HW]               = p;
            P[base + (size_t)(LL + 0*LL + l) * HW] = p * Ic0;
            P[base + (size_t)(LL + 1*LL + l) * HW] = p * Ic1;
            P[base + (size_t)(LL + 2*LL + l) * HW] = p * Ic2;
        }
    }
}

// ---- host ------------------------------------------------------------------
static inline void box_phase(float* P, float* tmp, int c0, int total, int chunk,
                             hipStream_t st) {
    for (int c = c0; c < c0 + total; c += chunk) {
        int n = c0 + total - c; if (n > chunk) n = chunk;
        dim3 gv(2 * (HH / VSEG), BB * n);
        dim3 gh(HH / TR, BB * n);
        vbox_k<<<gv, 256, 0, st>>>(P, tmp, c, n);
        hbox_k<<<gh, 256, 0, st>>>(tmp, P, c, n);
    }
}

extern "C" void kernel_launch(void* const* d_in, const int* in_sizes, int n_in,
                              void* d_out, int out_size, void* d_ws, size_t ws_size,
                              hipStream_t stream) {
    const float* E0   = (const float*)d_in[0];
    const float* Refs = (const float*)d_in[1];
    const float* Wmu  = (const float*)d_in[2];
    const float* epsp = (const float*)d_in[3];
    float* out = (float*)d_out;

    size_t planeB = (size_t)HW * 4;
    size_t Pb = (size_t)BB * NCH * planeB;     // 168 MB: p/Ip, box, a/b (in place)
    size_t Ab = (size_t)BB * 6 * planeB;       // 12 MB
    size_t Mb = (size_t)BB * 3 * planeB;       // 6 MB
    char* ws = (char*)d_ws;
    float* P    = (float*)ws;
    float* Ainv = (float*)(ws + Pb);
    float* mI   = (float*)(ws + Pb + Ab);
    float* tmp  = (float*)(ws + Pb + Ab + Mb);
    size_t fixed = Pb + Ab + Mb;
    size_t avail = ws_size > fixed ? ws_size - fixed : 0;
    int chunk = (int)(avail / ((size_t)BB * planeB));
    if (chunk > NCH) chunk = NCH;
    if (chunk < 1) chunk = 1;   // ws too small would be fatal anyway

    int nblk = (BB * HW) / 256;
    prod_k<<<nblk, 256, 0, stream>>>(P, Refs);
    box_phase(P, tmp, 0, 9, chunk, stream);                 // box I, I*I
    prep_k<<<nblk, 256, 0, stream>>>(P, Ainv, mI, epsp);
    e_k<<<nblk, 256, 0, stream>>>(P, E0, Refs, Wmu, out, 0); // Q0 -> p, Ip

    for (int t = 1; t <= 5; ++t) {
        box_phase(P, tmp, 0, NCH, chunk, stream);           // box p, Ip
        solve_k<<<nblk, 256, 0, stream>>>(P, Ainv, mI);     // -> a, b
        box_phase(P, tmp, 0, NCH, chunk, stream);           // box a, b
        e_k<<<nblk, 256, 0, stream>>>(P, E0, Refs, Wmu, out, t == 5 ? 2 : 1);
    }
}

// Round 3
// 3021.116 us; speedup vs baseline: 1.3470x; 1.3470x over previous
//
#include <hip/hip_runtime.h>
#include <hip/hip_bf16.h>

#define BB   2
#define LL   21
#define CC   3
#define HH   512
#define WW   512
#define RR   20
#define NCH  84            // LL + CC*LL planes per batch (p, then I_c*p)
#define HW   (HH*WW)       // 262144 = 2^18
#define VSEG 64            // rows per vbox thread strip
#define TR   8             // rows per hbox block (phase-2 plain hbox)
#define TRS  4             // rows per hbox_solve block
#define LROW 544           // 512 + 512/16 skew pad
#define CST  2177          // per-plane LDS stride in hbox_solve (odd -> bank shift)
#define SKW(i) ((i) + ((i) >> 4))

__device__ __forceinline__ float nrminv(int x, int y) {
    int cx = min(x + RR, WW - 1) - max(x - RR, 0) + 1;
    int cy = min(y + RR, HH - 1) - max(y - RR, 0) + 1;
    return 1.0f / (float)(cx * cy);
}
__device__ __forceinline__ void add4(float4& a, const float4 b) {
    a.x += b.x; a.y += b.y; a.z += b.z; a.w += b.w;
}
__device__ __forceinline__ void sub4(float4& a, const float4 b) {
    a.x -= b.x; a.y -= b.y; a.z -= b.z; a.w -= b.w;
}

// ---- products: I and I*I planes into P -------------------------------------
__global__ __launch_bounds__(256) void prod_k(float* __restrict__ P,
                                              const float* __restrict__ Refs) {
    int idx = blockIdx.x * 256 + threadIdx.x;
    int b = idx >> 18, pix = idx & (HW - 1);
    float I0 = Refs[((size_t)b * 3 + 0) * HW + pix];
    float I1 = Refs[((size_t)b * 3 + 1) * HW + pix];
    float I2 = Refs[((size_t)b * 3 + 2) * HW + pix];
    size_t base = (size_t)b * NCH * HW + pix;
    P[base + (size_t)0 * HW] = I0;
    P[base + (size_t)1 * HW] = I1;
    P[base + (size_t)2 * HW] = I2;
    P[base + (size_t)3 * HW] = I0 * I0;
    P[base + (size_t)4 * HW] = I0 * I1;
    P[base + (size_t)5 * HW] = I0 * I2;
    P[base + (size_t)6 * HW] = I1 * I1;
    P[base + (size_t)7 * HW] = I1 * I2;
    P[base + (size_t)8 * HW] = I2 * I2;
}

// ---- vertical box sum, float4 x 4-chain: P(planes) -> tmp(compact) ---------
// grouped==0: plane ch = l0 + j (linear). grouped==1: j -> (l, c) group of 4.
__global__ __launch_bounds__(256) void vbox_k(const float* __restrict__ src,
                                              float* __restrict__ dst,
                                              int l0, int n, int grouped) {
    int pp = blockIdx.y;
    int b, ch;
    if (grouped) {
        int g = n * 4;
        b = pp / g;
        int r = pp - b * g;
        int j = r >> 2, c = r & 3;
        int l = l0 + j;
        ch = (c == 0) ? l : (LL + (c - 1) * LL + l);
    } else {
        b = pp / n;
        ch = l0 + (pp - b * n);
    }
    const float4* s = (const float4*)(src + ((size_t)(b * NCH + ch)) * HW);
    float4* d = (float4*)(dst + (size_t)pp * HW);
    int xq = threadIdx.x & 127;                       // float4 column index
    int y0 = (blockIdx.x * 2 + (threadIdx.x >> 7)) * VSEG;
    float4 sum = {0.f, 0.f, 0.f, 0.f};
    int lo = y0 - RR; if (lo < 0) lo = 0;
    int hi = y0 + RR; if (hi > HH - 1) hi = HH - 1;
    for (int yy = lo; yy <= hi; ++yy) add4(sum, s[yy * 128 + xq]);
    d[y0 * 128 + xq] = sum;
    #pragma unroll 4
    for (int y = y0 + 1; y < y0 + VSEG; ++y) {
        int ya = y + RR, ys = y - RR - 1;
        if (ya < HH)  add4(sum, s[ya * 128 + xq]);
        if (ys >= 0)  sub4(sum, s[ys * 128 + xq]);
        d[y * 128 + xq] = sum;
    }
}

// ---- phase-1: horizontal box of (p, Ip0..2) + fused 3x3 solve -> b, a ------
__global__ __launch_bounds__(256) void hbox_solve_k(const float* __restrict__ tmp,
                                                    float* __restrict__ P,
                                                    const float* __restrict__ Ainv,
                                                    const float* __restrict__ mI,
                                                    int l0, int nl) {
    __shared__ float lin[4 * CST];
    __shared__ float lout[4 * CST];
    int pp = blockIdx.y;
    int b = pp / nl, j = pp - b * nl;
    int l = l0 + j;
    size_t tbase = ((size_t)(b * nl + j) * 4) * HW;
    int row0 = blockIdx.x * TRS;
    int tid = threadIdx.x;
    #pragma unroll
    for (int k = 0; k < (4 * TRS * WW) / 256; ++k) {
        int idx = tid + k * 256;
        int c = idx >> 11, rem = idx & 2047, rr = rem >> 9, xx = rem & 511;
        lin[c * CST + rr * LROW + SKW(xx)] =
            tmp[tbase + (size_t)c * HW + (size_t)(row0 + rr) * WW + xx];
    }
    __syncthreads();
    {
        int combo = tid >> 4, c = combo & 3, rr = combo >> 2;
        int xs = (tid & 15) * 32;
        const float* in = lin + c * CST + rr * LROW;
        float* op = lout + c * CST + rr * LROW;
        float sum = 0.f;
        #pragma unroll
        for (int t = -RR; t <= RR; ++t) {
            int i = xs + t;
            if (i >= 0 && i < WW) sum += in[SKW(i)];
        }
        op[SKW(xs)] = sum;
        #pragma unroll
        for (int k = 1; k < 32; ++k) {
            int xx = xs + k;
            int ia = xx + RR, is = xx - RR - 1;
            if (ia < WW)  sum += in[SKW(ia)];
            if (is >= 0)  sum -= in[SKW(is)];
            op[SKW(xx)] = sum;
        }
    }
    __syncthreads();
    #pragma unroll
    for (int k = 0; k < (TRS * WW) / 256; ++k) {
        int idx = tid + k * 256;
        int rr = idx >> 9, xx = idx & 511;
        int y = row0 + rr;
        int pix = y * WW + xx;
        float nrm = nrminv(xx, y);
        int lo = rr * LROW + SKW(xx);
        float mp   = lout[0 * CST + lo] * nrm;
        float bp0  = lout[1 * CST + lo] * nrm;
        float bp1  = lout[2 * CST + lo] * nrm;
        float bp2  = lout[3 * CST + lo] * nrm;
        size_t ab = (size_t)b * 6 * HW + pix;
        size_t mb = (size_t)b * 3 * HW + pix;
        float mi0 = mI[mb], mi1 = mI[mb + (size_t)HW], mi2 = mI[mb + (size_t)2 * HW];
        float cov0 = bp0 - mi0 * mp;
        float cov1 = bp1 - mi1 * mp;
        float cov2 = bp2 - mi2 * mp;
        float iv0 = Ainv[ab + (size_t)0 * HW];
        float iv1 = Ainv[ab + (size_t)1 * HW];
        float iv2 = Ainv[ab + (size_t)2 * HW];
        float iv3 = Ainv[ab + (size_t)3 * HW];
        float iv4 = Ainv[ab + (size_t)4 * HW];
        float iv5 = Ainv[ab + (size_t)5 * HW];
        float a0 = iv0 * cov0 + iv1 * cov1 + iv2 * cov2;
        float a1 = iv1 * cov0 + iv3 * cov1 + iv4 * cov2;
        float a2 = iv2 * cov0 + iv4 * cov1 + iv5 * cov2;
        float bb = mp - (a0 * mi0 + a1 * mi1 + a2 * mi2);
        size_t pbase = (size_t)b * NCH * HW + pix;
        P[pbase + (size_t)l * HW]                 = bb;
        P[pbase + (size_t)(LL + 0 * LL + l) * HW] = a0;
        P[pbase + (size_t)(LL + 1 * LL + l) * HW] = a1;
        P[pbase + (size_t)(LL + 2 * LL + l) * HW] = a2;
    }
}

// ---- phase-2 horizontal box: tmp(compact) -> P(strided planes) -------------
__global__ __launch_bounds__(256) void hbox_k(const float* __restrict__ src,
                                              float* __restrict__ dst, int c0, int n) {
    __shared__ float lin[TR * LROW];
    __shared__ float lout[TR * LROW];
    int pp = blockIdx.y;
    int b = pp / n, j = pp % n;
    const float* s = src + (size_t)pp * HW + (size_t)blockIdx.x * (TR * WW);
    float* d = dst + ((size_t)(b * NCH + c0 + j)) * HW + (size_t)blockIdx.x * (TR * WW);
    int tid = threadIdx.x;
    #pragma unroll
    for (int k = 0; k < (TR * WW) / 256; ++k) {
        int idx = tid + k * 256;
        int row = idx >> 9, xx = idx & (WW - 1);
        lin[row * LROW + SKW(xx)] = s[idx];
    }
    __syncthreads();
    int row = tid >> 5;
    int x0  = (tid & 31) << 4;
    const float* in = lin + row * LROW;
    float* op = lout + row * LROW;
    float sum = 0.f;
    #pragma unroll
    for (int t = -RR; t <= RR; ++t) {
        int i = x0 + t;
        if (i >= 0 && i < WW) sum += in[SKW(i)];
    }
    op[SKW(x0)] = sum;
    #pragma unroll
    for (int k = 1; k < 16; ++k) {
        int xx = x0 + k;
        int ia = xx + RR, is = xx - RR - 1;
        if (ia < WW)  sum += in[SKW(ia)];
        if (is >= 0)  sum -= in[SKW(is)];
        op[SKW(xx)] = sum;
    }
    __syncthreads();
    #pragma unroll
    for (int k = 0; k < (TR * WW) / 256; ++k) {
        int idx = tid + k * 256;
        int r2 = idx >> 9, xx = idx & (WW - 1);
        d[idx] = lout[r2 * LROW + SKW(xx)];
    }
}

// ---- precompute mI and Ainv = (var_I + eps I)^-1 (symmetric, 6 planes) -----
__global__ __launch_bounds__(256) void prep_k(const float* __restrict__ P,
                                              float* __restrict__ Ainv, float* __restrict__ mI,
                                              const float* __restrict__ epsp) {
    int idx = blockIdx.x * 256 + threadIdx.x;
    int b = idx >> 18, pix = idx & (HW - 1);
    int x = pix & (WW - 1), y = pix >> 9;
    float nrm = nrminv(x, y);
    float eps = epsp[0];
    size_t base = (size_t)b * NCH * HW + pix;
    float m0 = P[base + (size_t)0 * HW] * nrm;
    float m1 = P[base + (size_t)1 * HW] * nrm;
    float m2 = P[base + (size_t)2 * HW] * nrm;
    float v00 = P[base + (size_t)3 * HW] * nrm - m0 * m0 + eps;
    float v01 = P[base + (size_t)4 * HW] * nrm - m0 * m1;
    float v02 = P[base + (size_t)5 * HW] * nrm - m0 * m2;
    float v11 = P[base + (size_t)6 * HW] * nrm - m1 * m1 + eps;
    float v12 = P[base + (size_t)7 * HW] * nrm - m1 * m2;
    float v22 = P[base + (size_t)8 * HW] * nrm - m2 * m2 + eps;
    float c00 = v11 * v22 - v12 * v12;
    float c01 = v02 * v12 - v01 * v22;
    float c02 = v01 * v12 - v02 * v11;
    float c11 = v00 * v22 - v02 * v02;
    float c12 = v01 * v02 - v00 * v12;
    float c22 = v00 * v11 - v01 * v01;
    float det = v00 * c00 + v01 * c01 + v02 * c02;
    float id = 1.0f / det;
    size_t ab = (size_t)b * 6 * HW + pix;
    Ainv[ab + (size_t)0 * HW] = c00 * id;
    Ainv[ab + (size_t)1 * HW] = c01 * id;
    Ainv[ab + (size_t)2 * HW] = c02 * id;
    Ainv[ab + (size_t)3 * HW] = c11 * id;
    Ainv[ab + (size_t)4 * HW] = c12 * id;
    Ainv[ab + (size_t)5 * HW] = c22 * id;
    size_t mb = (size_t)b * 3 * HW + pix;
    mI[mb]                 = m0;
    mI[mb + (size_t)HW]    = m1;
    mI[mb + (size_t)2*HW]  = m2;
}

// ---- fused: q = (boxa.I + boxb)/Nrm, E=E0+q, Q=softmax(-E), p=W.Q, Ip ------
// mode 0: init (skip q, E=E0);  mode 1: mid;  mode 2: last (write Q out)
__global__ __launch_bounds__(256) void e_k(float* __restrict__ P,
                                           const float* __restrict__ E0,
                                           const float* __restrict__ Refs,
                                           const float* __restrict__ Wf,
                                           float* __restrict__ out, int mode) {
    int idx = blockIdx.x * 256 + threadIdx.x;
    int b = idx >> 18, pix = idx & (HW - 1);
    int x = pix & (WW - 1), y = pix >> 9;
    float nrm = nrminv(x, y);
    size_t base  = (size_t)b * NCH * HW + pix;
    size_t ebase = (size_t)b * LL * HW + pix;
    float Ic0 = Refs[((size_t)b * 3 + 0) * HW + pix];
    float Ic1 = Refs[((size_t)b * 3 + 1) * HW + pix];
    float Ic2 = Refs[((size_t)b * 3 + 2) * HW + pix];
    float Ev[LL];
    float mmax = -1e30f;
    #pragma unroll
    for (int l = 0; l < LL; ++l) {
        float val = E0[ebase + (size_t)l * HW];
        if (mode != 0) {
            float s = P[base + (size_t)l * HW];
            s += P[base + (size_t)(LL + 0*LL + l) * HW] * Ic0;
            s += P[base + (size_t)(LL + 1*LL + l) * HW] * Ic1;
            s += P[base + (size_t)(LL + 2*LL + l) * HW] * Ic2;
            val += s * nrm;
        }
        float nv = -val;
        Ev[l] = nv;
        mmax = fmaxf(mmax, nv);
    }
    float ssum = 0.f;
    #pragma unroll
    for (int l = 0; l < LL; ++l) { float e = __expf(Ev[l] - mmax); Ev[l] = e; ssum += e; }
    float inv = 1.0f / ssum;
    if (mode == 2) {
        #pragma unroll
        for (int l = 0; l < LL; ++l)
            out[ebase + (size_t)l * HW] = Ev[l] * inv;
    } else {
        #pragma unroll
        for (int l = 0; l < LL; ++l) Ev[l] *= inv;      // Ev now holds Q
        #pragma unroll
        for (int l = 0; l < LL; ++l) {
            float p = 0.f;
            #pragma unroll
            for (int m = 0; m < LL; ++m) p += Wf[l * LL + m] * Ev[m];
            P[base + (size_t)l * HW]               = p;
            P[base + (size_t)(LL + 0*LL + l) * HW] = p * Ic0;
            P[base + (size_t)(LL + 1*LL + l) * HW] = p * Ic1;
            P[base + (size_t)(LL + 2*LL + l) * HW] = p * Ic2;
        }
    }
}

// ---- host ------------------------------------------------------------------
extern "C" void kernel_launch(void* const* d_in, const int* in_sizes, int n_in,
                              void* d_out, int out_size, void* d_ws, size_t ws_size,
                              hipStream_t stream) {
    const float* E0   = (const float*)d_in[0];
    const float* Refs = (const float*)d_in[1];
    const float* Wmu  = (const float*)d_in[2];
    const float* epsp = (const float*)d_in[3];
    float* out = (float*)d_out;

    size_t planeB = (size_t)HW * 4;
    size_t Pb = (size_t)BB * NCH * planeB;     // 168 MB
    size_t Ab = (size_t)BB * 6 * planeB;       // 12 MB
    size_t Mb = (size_t)BB * 3 * planeB;       // 6 MB
    char* ws = (char*)d_ws;
    float* P    = (float*)ws;
    float* Ainv = (float*)(ws + Pb);
    float* mI   = (float*)(ws + Pb + Ab);
    float* tmp  = (float*)(ws + Pb + Ab + Mb);
    size_t fixed = Pb + Ab + Mb;
    size_t avail = ws_size > fixed ? ws_size - fixed : 0;
    int chunk = (int)(avail / ((size_t)BB * planeB));       // linear planes
    if (chunk > NCH) chunk = NCH;
    if (chunk < 1) chunk = 1;
    int nlmax = (int)(avail / ((size_t)BB * 4 * planeB));   // l-groups (4 planes)
    if (nlmax > LL) nlmax = LL;
    if (nlmax < 1) nlmax = 1;

    int nblk = (BB * HW) / 256;
    prod_k<<<nblk, 256, 0, stream>>>(P, Refs);
    // box I, I*I (9 planes, linear)
    for (int c = 0; c < 9; c += chunk) {
        int n = 9 - c; if (n > chunk) n = chunk;
        vbox_k<<<dim3(HH / (2 * VSEG), BB * n), 256, 0, stream>>>(P, tmp, c, n, 0);
        hbox_k<<<dim3(HH / TR, BB * n), 256, 0, stream>>>(tmp, P, c, n);
    }
    prep_k<<<nblk, 256, 0, stream>>>(P, Ainv, mI, epsp);
    e_k<<<nblk, 256, 0, stream>>>(P, E0, Refs, Wmu, out, 0);

    for (int t = 1; t <= 5; ++t) {
        // phase 1: box p,Ip (grouped by l) + fused solve -> b,a
        for (int l0 = 0; l0 < LL; l0 += nlmax) {
            int nl = LL - l0; if (nl > nlmax) nl = nlmax;
            vbox_k<<<dim3(HH / (2 * VSEG), BB * nl * 4), 256, 0, stream>>>(P, tmp, l0, nl, 1);
            hbox_solve_k<<<dim3(HH / TRS, BB * nl), 256, 0, stream>>>(tmp, P, Ainv, mI, l0, nl);
        }
        // phase 2: box b,a (linear)
        for (int c = 0; c < NCH; c += chunk) {
            int n = NCH - c; if (n > chunk) n = chunk;
            vbox_k<<<dim3(HH / (2 * VSEG), BB * n), 256, 0, stream>>>(P, tmp, c, n, 0);
            hbox_k<<<dim3(HH / TR, BB * n), 256, 0, stream>>>(tmp, P, c, n);
        }
        e_k<<<nblk, 256, 0, stream>>>(P, E0, Refs, Wmu, out, t == 5 ? 2 : 1);
    }
}